// Round 18
// baseline (115.668 us; speedup 1.0000x reference)
//
#include <hip/hip_runtime.h>
#include <math.h>

typedef unsigned short u16;
typedef unsigned int u32;
typedef __bf16 bf16x8 __attribute__((ext_vector_type(8)));
typedef float f32x4 __attribute__((ext_vector_type(4)));
typedef unsigned short u16x8 __attribute__((ext_vector_type(8)));
typedef unsigned int u32x2 __attribute__((ext_vector_type(2)));

static __device__ __forceinline__ u16 f2bf(float f) {
  unsigned int u = __builtin_bit_cast(unsigned int, f);
  u = (u + 0x7FFFu + ((u >> 16) & 1u)) >> 16;
  return (u16)u;
}
static __device__ __forceinline__ float bf2f(u16 u) {
  unsigned int x = ((unsigned int)u) << 16;
  return __builtin_bit_cast(float, x);
}
static __device__ __forceinline__ u16 f2bfh(float f) {
  __bf16 b = (__bf16)f;
  return __builtin_bit_cast(u16, b);
}
static __device__ __forceinline__ void gll16(const u16* g, u16* l) {
  __builtin_amdgcn_global_load_lds((const __attribute__((address_space(1))) u32*)g,
                                   (__attribute__((address_space(3))) u32*)l, 16, 0, 0);
}

#define QSCALE 0.18033688011112042f

// ---------------- prep: f32->bf16 for x and W + RoPE cos/sin table (disjoint ranges) ----
__global__ __launch_bounds__(256) void prep_k(const float* __restrict__ a, u16* __restrict__ da, int n4a,
                                              const float* __restrict__ b, u16* __restrict__ db, int n4b,
                                              float2* __restrict__ tab) {
  int idx = blockIdx.x * 256 + threadIdx.x;
  if (idx < n4a + n4b) {
    const float* src; u16* dst; int i;
    if (idx < n4a) { src = a; dst = da; i = idx; }
    else { src = b; dst = db; i = idx - n4a; }
    float4 v = ((const float4*)src)[i];
    ushort4 r;
    r.x = f2bf(v.x); r.y = f2bf(v.y); r.z = f2bf(v.z); r.w = f2bf(v.w);
    ((ushort4*)dst)[i] = r;
  } else {
    int e = idx - n4a - n4b;
    if (e < 2048 * 32) {
      int s = e >> 5, j = e & 31;
      float sn, cs;
      sincosf((float)s * expf(-(float)j * (9.21034037198f / 32.0f)), &sn, &cs);
      tab[e] = make_float2(cs, sn);
    }
  }
}

// ---------------- QKV GEMM (64x128 tile), double-buffered gll16, fused norm/rope ----
__global__ __launch_bounds__(256) void gemm_qkv(const u16* __restrict__ A, const u16* __restrict__ B,
                                                const float* __restrict__ qw, const float* __restrict__ kw,
                                                const float2* __restrict__ tab,
                                                u16* __restrict__ Qo, u16* __restrict__ Ko,
                                                u16* __restrict__ Vt, int K) {
  __shared__ __align__(16) u16 sA[2][64 * 32];
  __shared__ __align__(16) u16 sB[2][128 * 32];
  const int tid = threadIdx.x;
  const int w = tid >> 6, lane = tid & 63, l15 = lane & 15, lg = lane >> 4;
  const int m0 = blockIdx.x * 64, n0 = blockIdx.y * 128;
  const int wm = (w >> 1) * 32, wn = (w & 1) * 64;

  f32x4 acc[2][4] = {};

  int sArow, sAcol;
  {
    int p = tid * 16;
    int row = p >> 6, oo = p & 63;
    int ol = oo ^ (((row >> 1) & 3) << 4);
    sArow = row; sAcol = ol >> 1;
  }
  int sBrow[2], sBcol[2];
#pragma unroll
  for (int i = 0; i < 2; ++i) {
    int p = i * 4096 + tid * 16;
    int row = p >> 6, oo = p & 63;
    int ol = oo ^ (((row >> 1) & 3) << 4);
    sBrow[i] = row; sBcol[i] = ol >> 1;
  }
  int aoff[2], boff[4];
  const int kb = lg * 16;
#pragma unroll
  for (int m = 0; m < 2; ++m) {
    int r = wm + m * 16 + l15;
    aoff[m] = r * 64 + (kb ^ (((r >> 1) & 3) << 4));
  }
#pragma unroll
  for (int n = 0; n < 4; ++n) {
    int r = wn + n * 16 + l15;
    boff[n] = r * 64 + (kb ^ (((r >> 1) & 3) << 4));
  }

  // prologue: fill buffer 0
  gll16(A + (size_t)(m0 + sArow) * K + sAcol, (u16*)((char*)sA[0] + tid * 16));
#pragma unroll
  for (int i = 0; i < 2; ++i)
    gll16(B + (size_t)(n0 + sBrow[i]) * K + sBcol[i], (u16*)((char*)sB[0] + i * 4096 + tid * 16));
  __syncthreads();

  int cur = 0;
  for (int k0 = 0; k0 < K; k0 += 32) {
    // issue-early DMA for next k-tile into the other buffer
    if (k0 + 32 < K) {
      gll16(A + (size_t)(m0 + sArow) * K + (k0 + 32) + sAcol, (u16*)((char*)sA[cur ^ 1] + tid * 16));
#pragma unroll
      for (int i = 0; i < 2; ++i)
        gll16(B + (size_t)(n0 + sBrow[i]) * K + (k0 + 32) + sBcol[i],
              (u16*)((char*)sB[cur ^ 1] + i * 4096 + tid * 16));
    }
    bf16x8 af[2], bfr[4];
#pragma unroll
    for (int m = 0; m < 2; ++m) af[m] = *(const bf16x8*)((const char*)sA[cur] + aoff[m]);
#pragma unroll
    for (int n = 0; n < 4; ++n) bfr[n] = *(const bf16x8*)((const char*)sB[cur] + boff[n]);
#pragma unroll
    for (int m = 0; m < 2; ++m)
#pragma unroll
      for (int n = 0; n < 4; ++n)
        acc[m][n] = __builtin_amdgcn_mfma_f32_16x16x32_bf16(af[m], bfr[n], acc[m][n], 0, 0, 0);
    __syncthreads();   // drains DMA (vmcnt) + gates buffer reuse
    cur ^= 1;
  }

  const int he = (n0 + wn) >> 6;   // wave-uniform head index 0..23
  if (he < 20) {
    const float* wnorm = (he < 16) ? qw : kw;
    const float oscale = (he < 16) ? QSCALE : 1.0f;
    float wv[4];
#pragma unroll
    for (int n = 0; n < 4; ++n) wv[n] = wnorm[n * 16 + l15];
    float2 tj[4];
#pragma unroll
    for (int m = 0; m < 2; ++m)
#pragma unroll
      for (int i = 0; i < 4; ++i) {
        const int gr = m0 + wm + m * 16 + lg * 4 + i;
        const int s = gr & 2047, bb = gr >> 11;
        float ss = 0.f;
#pragma unroll
        for (int n = 0; n < 4; ++n) ss += acc[m][n][i] * acc[m][n][i];
        ss += __shfl_xor(ss, 8); ss += __shfl_xor(ss, 4);
        ss += __shfl_xor(ss, 2); ss += __shfl_xor(ss, 1);
        const float r = rsqrtf(ss * (1.0f / 64.0f) + 1.1920929e-7f);
#pragma unroll
        for (int n = 0; n < 4; ++n) tj[n] = tab[s * 32 + n * 8 + (l15 >> 1)];
        u16* orow = (he < 16)
          ? Qo + ((size_t)(bb * 16 + he) * 2048 + s) * 64 + l15
          : Ko + ((size_t)(bb * 4 + (he - 16)) * 2048 + s) * 64 + l15;
#pragma unroll
        for (int n = 0; n < 4; ++n) {
          float xn = acc[m][n][i] * r * wv[n];
          float p = __shfl_xor(xn, 1);
          float outv = ((l15 & 1) == 0) ? (xn * tj[n].x - p * tj[n].y)
                                        : (xn * tj[n].x + p * tj[n].y);
          orow[n * 16] = f2bf(outv * oscale);
        }
      }
  } else {
    // V: write transposed Vt[bh][d][s] directly
#pragma unroll
    for (int m = 0; m < 2; ++m)
#pragma unroll
      for (int i = 0; i < 4; ++i) {
        const int gr = m0 + wm + m * 16 + lg * 4 + i;
        const int s = gr & 2047, bb = gr >> 11;
        u16* vcol = Vt + ((size_t)(bb * 4 + (he - 20)) * 64 + l15) * 2048 + s;
#pragma unroll
        for (int n = 0; n < 4; ++n) vcol[(size_t)n * 16 * 2048] = f2bf(acc[m][n][i]);
      }
  }
}

// ---------------- Flash attention: r15 body (paired q-tiles + KV-parity, 24.5 KB LDS) ----
__global__ __launch_bounds__(256) void attn_fwd_pair(const u16* __restrict__ Q, const u16* __restrict__ Kg,
                                                     const u16* __restrict__ Vt,
                                                     u16* __restrict__ accP, float* __restrict__ lP) {
  __shared__ __align__(16) u16 sK[64 * 64];
  __shared__ __align__(16) u16 sV[64 * 64];
  __shared__ __align__(16) u16 sP[4][16 * 64];

  const int tid = threadIdx.x;
  const int w = tid >> 6, lane = tid & 63;
  const int l15 = lane & 15, lg = lane >> 4;
  const int qiA = blockIdx.x;
  const int qiB = 31 - qiA;
  const int z = blockIdx.z;
  const int bh = blockIdx.y, b = bh >> 4, h = bh & 15, kvh = h >> 2;

  const u16* Qp = Q + (size_t)(b * 16 + h) * 2048 * 64;
  const u16* Kp = Kg + (size_t)(b * 4 + kvh) * 2048 * 64;
  const u16* Vp = Vt + (size_t)(b * 4 + kvh) * 64 * 2048;

  const int q0s[2] = {qiA * 64, qiB * 64};
  bf16x8 qa[2][2];
#pragma unroll
  for (int s = 0; s < 2; ++s) {
    const u16* qrow = Qp + (size_t)(q0s[s] + w * 16 + l15) * 64 + lg * 8;
    qa[s][0] = *(const bf16x8*)qrow;
    qa[s][1] = *(const bf16x8*)(qrow + 32);
  }

  f32x4 acc[2][4] = {};
  float l_s[2] = {0.f, 0.f};

  const int srw = tid >> 2;
  const int scb = (tid & 3) * 32;
  const int swzS = (srw & 7) << 4;
  const int st0 = srw * 128 + (scb ^ swzS);
  const int st1 = srw * 128 + ((scb + 16) ^ swzS);
  const u16* kgp = Kp + (size_t)srw * 64 + (tid & 3) * 16;
  const u16* vgp = Vp + (size_t)srw * 2048 + (tid & 3) * 16;

  const int swzF = (l15 & 7) << 4;
  const int fo0 = (lg * 16) ^ swzF;
  const int fo1 = (64 + lg * 16) ^ swzF;

  u16x8 kr0 = *(const u16x8*)(kgp + (size_t)z * 64 * 64), kr1 = *(const u16x8*)(kgp + (size_t)z * 64 * 64 + 8);
  u16x8 vr0 = *(const u16x8*)(vgp + z * 64),              vr1 = *(const u16x8*)(vgp + z * 64 + 8);

  for (int t = z; t <= qiB; t += 2) {
    __syncthreads();
    *(u16x8*)((char*)sK + st0) = kr0; *(u16x8*)((char*)sK + st1) = kr1;
    *(u16x8*)((char*)sV + st0) = vr0; *(u16x8*)((char*)sV + st1) = vr1;
    __syncthreads();

    if (t + 2 <= qiB) {
      const u16* kg = kgp + (size_t)(t + 2) * 64 * 64;
      const u16* vg = vgp + (t + 2) * 64;
      kr0 = *(const u16x8*)kg; kr1 = *(const u16x8*)(kg + 8);
      vr0 = *(const u16x8*)vg; vr1 = *(const u16x8*)(vg + 8);
    }

    bf16x8 kf[4][2], vf[4][2];
#pragma unroll
    for (int ct = 0; ct < 4; ++ct) {
      const char* krow = (const char*)sK + (ct * 16 + l15) * 128;
      const char* vrow = (const char*)sV + (ct * 16 + l15) * 128;
      kf[ct][0] = *(const bf16x8*)(krow + fo0);
      kf[ct][1] = *(const bf16x8*)(krow + fo1);
      vf[ct][0] = *(const bf16x8*)(vrow + fo0);
      vf[ct][1] = *(const bf16x8*)(vrow + fo1);
    }

#pragma unroll
    for (int s = 0; s < 2; ++s) {
      if (s == 0 && t > qiA) continue;
      const int diag = s ? qiB : qiA;

      f32x4 st[4];
#pragma unroll
      for (int ct = 0; ct < 4; ++ct) {
        f32x4 s4 = {};
        s4 = __builtin_amdgcn_mfma_f32_16x16x32_bf16(kf[ct][0], qa[s][0], s4, 0, 0, 0);
        s4 = __builtin_amdgcn_mfma_f32_16x16x32_bf16(kf[ct][1], qa[s][1], s4, 0, 0, 0);
        st[ct] = s4;
      }

      if (t == diag) {
        const int ql = w * 16 + l15;
#pragma unroll
        for (int ct = 0; ct < 4; ++ct)
#pragma unroll
          for (int i = 0; i < 4; ++i)
            st[ct][i] = (ct * 16 + lg * 4 + i <= ql) ? st[ct][i] : -1e30f;
      }

      float ls = 0.f;
      const int swzP = (l15 & 7) << 4;
      char* prow = (char*)sP[w] + l15 * 128;
#pragma unroll
      for (int ct = 0; ct < 4; ++ct) {
        float p0 = exp2f(st[ct][0]), p1 = exp2f(st[ct][1]);
        float p2 = exp2f(st[ct][2]), p3 = exp2f(st[ct][3]);
        ls += (p0 + p1) + (p2 + p3);
        u32 lo = (u32)f2bfh(p0) | ((u32)f2bfh(p1) << 16);
        u32 hi = (u32)f2bfh(p2) | ((u32)f2bfh(p3) << 16);
        *(u32x2*)(prow + ((ct * 32 + lg * 8) ^ swzP)) = (u32x2){lo, hi};
      }
      l_s[s] += ls;

      bf16x8 pa0 = *(const bf16x8*)(prow + ((lg * 16) ^ swzP));
      bf16x8 pa1 = *(const bf16x8*)(prow + ((64 + lg * 16) ^ swzP));

#pragma unroll
      for (int n = 0; n < 4; ++n) {
        acc[s][n] = __builtin_amdgcn_mfma_f32_16x16x32_bf16(pa0, vf[n][0], acc[s][n], 0, 0, 0);
        acc[s][n] = __builtin_amdgcn_mfma_f32_16x16x32_bf16(pa1, vf[n][1], acc[s][n], 0, 0, 0);
      }
    }
  }

#pragma unroll
  for (int s = 0; s < 2; ++s) {
    float lv = l_s[s];
    lv += __shfl_xor(lv, 16);
    lv += __shfl_xor(lv, 32);
    if (lg == 0) {
      int qrow = q0s[s] + w * 16 + l15;
      lP[((size_t)z * 4096 + b * 2048 + qrow) * 16 + h] = lv;
    }
#pragma unroll
    for (int i = 0; i < 4; ++i) {
      int srowg = q0s[s] + w * 16 + lg * 4 + i;
      size_t rowbase = (size_t)z * 4096 + b * 2048 + srowg;
      u16* orow = accP + rowbase * 1024 + h * 64 + l15;
#pragma unroll
      for (int n = 0; n < 4; ++n) orow[n * 16] = f2bfh(acc[s][n][i]);
    }
  }
}

// ---------------- invg: ivg[token][h] = sigmoid(x[:12]@gw[h]) / (l0+l1) ----------------
__global__ __launch_bounds__(256) void invg_k(const float* __restrict__ lP, const float* __restrict__ x,
                                              const float* __restrict__ gw, float* __restrict__ ivg) {
  int i = blockIdx.x * 256 + threadIdx.x;   // 4096*16
  int token = i >> 4, h = i & 15;
  float l = lP[i] + lP[4096 * 16 + i];
  float gd = 0.f;
#pragma unroll
  for (int j = 0; j < 12; ++j) gd += x[(size_t)token * 1024 + j] * gw[h * 12 + j];
  ivg[i] = (1.0f / (1.0f + __expf(-gd))) / l;
}

// ---------------- out-proj GEMM with fused combine: A = (a0+a1)*ivg, dbuf staging ----
__global__ __launch_bounds__(256) void gemm_out(const u16* __restrict__ accP, const float* __restrict__ ivg,
                                                const u16* __restrict__ B, float* __restrict__ C,
                                                int N, int K) {
  __shared__ __align__(16) u16 sA[2][64 * 32];
  __shared__ __align__(16) u16 sB[2][128 * 32];
  const int tid = threadIdx.x;
  const int w = tid >> 6, lane = tid & 63, l15 = lane & 15;
  const int m0 = blockIdx.x * 64, n0 = blockIdx.y * 128;
  const int wm = (w >> 1) * 32, wn = (w & 1) * 64;

  f32x4 acc[2][4] = {};

  // A reg-staging: thread fills LDS bytes [tid*16, +16) with combined data from the
  // swizzled global column (same swizzle the fragment reads expect).
  const int sArow = tid >> 2;
  const int scolA = ((((tid & 3) * 16) ^ (((sArow >> 1) & 3) << 4)) >> 1);
  const int tokenA = m0 + sArow;
  const u16* a0p = accP + (size_t)tokenA * 1024;
  const u16* a1p = accP + (size_t)(4096 + tokenA) * 1024;

  int sBrow[2], sBcol[2];
#pragma unroll
  for (int i = 0; i < 2; ++i) {
    int p = i * 4096 + tid * 16;
    int row = p >> 6, oo = p & 63;
    int ol = oo ^ (((row >> 1) & 3) << 4);
    sBrow[i] = row; sBcol[i] = ol >> 1;
  }
  int aoff[2], boff[4];
  const int kb = (lane >> 4) * 16;
#pragma unroll
  for (int m = 0; m < 2; ++m) {
    int r = wm + m * 16 + l15;
    aoff[m] = r * 64 + (kb ^ (((r >> 1) & 3) << 4));
  }
#pragma unroll
  for (int n = 0; n < 4; ++n) {
    int r = wn + n * 16 + l15;
    boff[n] = r * 64 + (kb ^ (((r >> 1) & 3) << 4));
  }

  auto loadA = [&](int k0) -> u16x8 {
    const int e = k0 + scolA;            // 8-aligned, never crosses a 64-boundary
    const float g = ivg[tokenA * 16 + (e >> 6)];
    u16x8 a0 = *(const u16x8*)(a0p + e);
    u16x8 a1 = *(const u16x8*)(a1p + e);
    u16x8 r;
#pragma unroll
    for (int j = 0; j < 8; ++j) r[j] = f2bf((bf2f(a0[j]) + bf2f(a1[j])) * g);
    return r;
  };

  // prologue: fill buffer 0
  {
    u16x8 va = loadA(0);
    *(u16x8*)((char*)sA[0] + tid * 16) = va;
  }
#pragma unroll
  for (int i = 0; i < 2; ++i)
    gll16(B + (size_t)(n0 + sBrow[i]) * K + sBcol[i], (u16*)((char*)sB[0] + i * 4096 + tid * 16));
  __syncthreads();

  int cur = 0;
  for (int k0 = 0; k0 < K; k0 += 32) {
    u16x8 va;
    const bool more = (k0 + 32 < K);
    if (more) {
#pragma unroll
      for (int i = 0; i < 2; ++i)
        gll16(B + (size_t)(n0 + sBrow[i]) * K + (k0 + 32) + sBcol[i],
              (u16*)((char*)sB[cur ^ 1] + i * 4096 + tid * 16));
      va = loadA(k0 + 32);
    }
    bf16x8 af[2], bfr[4];
#pragma unroll
    for (int m = 0; m < 2; ++m) af[m] = *(const bf16x8*)((const char*)sA[cur] + aoff[m]);
#pragma unroll
    for (int n = 0; n < 4; ++n) bfr[n] = *(const bf16x8*)((const char*)sB[cur] + boff[n]);
#pragma unroll
    for (int m = 0; m < 2; ++m)
#pragma unroll
      for (int n = 0; n < 4; ++n)
        acc[m][n] = __builtin_amdgcn_mfma_f32_16x16x32_bf16(af[m], bfr[n], acc[m][n], 0, 0, 0);
    if (more) *(u16x8*)((char*)sA[cur ^ 1] + tid * 16) = va;
    __syncthreads();
    cur ^= 1;
  }

#pragma unroll
  for (int m = 0; m < 2; ++m)
#pragma unroll
    for (int i = 0; i < 4; ++i) {
      int gr = m0 + wm + m * 16 + (lane >> 4) * 4 + i;
      float* crow = C + (size_t)gr * N + n0 + wn + l15;
#pragma unroll
      for (int n = 0; n < 4; ++n) crow[n * 16] = acc[m][n][i];
    }
}

// ---------------- launch ----------------
extern "C" void kernel_launch(void* const* d_in, const int* in_sizes, int n_in,
                              void* d_out, int out_size, void* d_ws, size_t ws_size,
                              hipStream_t stream) {
  const float* x  = (const float*)d_in[0];
  const float* Wf = (const float*)d_in[1];
  const float* qw = (const float*)d_in[2];
  const float* kw = (const float*)d_in[3];
  const float* gw = (const float*)d_in[4];
  float* out = (float*)d_out;

  char* ws = (char*)d_ws;
  size_t off = 0;
  auto alloc = [&](size_t bytes) { void* p = ws + off; off += (bytes + 255) & ~(size_t)255; return p; };

  u16*    xb   = (u16*)alloc((size_t)4096 * 1024 * 2);
  u16*    wb   = (u16*)alloc((size_t)2560 * 1024 * 2);
  float2* tab  = (float2*)alloc((size_t)2048 * 32 * 8);
  u16*    Qb   = (u16*)alloc((size_t)2 * 16 * 2048 * 64 * 2);
  u16*    Kb   = (u16*)alloc((size_t)2 * 4 * 2048 * 64 * 2);
  u16*    Vtb  = (u16*)alloc((size_t)2 * 4 * 2048 * 64 * 2);
  float*  lP   = (float*)alloc((size_t)2 * 4096 * 16 * 4);
  u16*    accP = (u16*)alloc((size_t)2 * 4096 * 1024 * 2);
  float*  ivg  = (float*)alloc((size_t)4096 * 16 * 4);

  const int n4a = 4096 * 1024 / 4, n4b = 2560 * 1024 / 4;
  const int prep_total = n4a + n4b + 2048 * 32;
  prep_k<<<dim3((prep_total + 255) / 256), dim3(256), 0, stream>>>(x, xb, n4a, Wf, wb, n4b, tab);
  gemm_qkv<<<dim3(64, 12), dim3(256), 0, stream>>>(xb, wb, qw, kw, tab, Qb, Kb, Vtb, 1024);
  attn_fwd_pair<<<dim3(16, 32, 2), dim3(256), 0, stream>>>(Qb, Kb, Vtb, accP, lP);
  invg_k<<<dim3(256), dim3(256), 0, stream>>>(lP, x, gw, ivg);
  gemm_out<<<dim3(64, 8), dim3(256), 0, stream>>>(accP, ivg, wb + (size_t)1536 * 1024, out, 1024, 1024);
}

// Round 19
// 112.937 us; speedup vs baseline: 1.0242x; 1.0242x over previous
//
#include <hip/hip_runtime.h>
#include <math.h>

typedef unsigned short u16;
typedef unsigned int u32;
typedef __bf16 bf16x8 __attribute__((ext_vector_type(8)));
typedef float f32x4 __attribute__((ext_vector_type(4)));
typedef unsigned short u16x8 __attribute__((ext_vector_type(8)));
typedef unsigned int u32x2 __attribute__((ext_vector_type(2)));

static __device__ __forceinline__ u16 f2bf(float f) {
  unsigned int u = __builtin_bit_cast(unsigned int, f);
  u = (u + 0x7FFFu + ((u >> 16) & 1u)) >> 16;
  return (u16)u;
}
static __device__ __forceinline__ float bf2f(u16 u) {
  unsigned int x = ((unsigned int)u) << 16;
  return __builtin_bit_cast(float, x);
}
static __device__ __forceinline__ u16 f2bfh(float f) {
  __bf16 b = (__bf16)f;
  return __builtin_bit_cast(u16, b);
}
static __device__ __forceinline__ void gll16(const u16* g, u16* l) {
  __builtin_amdgcn_global_load_lds((const __attribute__((address_space(1))) u32*)g,
                                   (__attribute__((address_space(3))) u32*)l, 16, 0, 0);
}

#define QSCALE 0.18033688011112042f

// ---------------- prep: f32->bf16 for x and W + RoPE cos/sin table (disjoint ranges) ----
__global__ __launch_bounds__(256) void prep_k(const float* __restrict__ a, u16* __restrict__ da, int n4a,
                                              const float* __restrict__ b, u16* __restrict__ db, int n4b,
                                              float2* __restrict__ tab) {
  int idx = blockIdx.x * 256 + threadIdx.x;
  if (idx < n4a + n4b) {
    const float* src; u16* dst; int i;
    if (idx < n4a) { src = a; dst = da; i = idx; }
    else { src = b; dst = db; i = idx - n4a; }
    float4 v = ((const float4*)src)[i];
    ushort4 r;
    r.x = f2bf(v.x); r.y = f2bf(v.y); r.z = f2bf(v.z); r.w = f2bf(v.w);
    ((ushort4*)dst)[i] = r;
  } else {
    int e = idx - n4a - n4b;
    if (e < 2048 * 32) {
      int s = e >> 5, j = e & 31;
      float sn, cs;
      sincosf((float)s * expf(-(float)j * (9.21034037198f / 32.0f)), &sn, &cs);
      tab[e] = make_float2(cs, sn);
    }
  }
}

// ---------------- bf16 NT GEMM, 64x128 tile (out-proj): gll16 staging ----------------
__global__ __launch_bounds__(256) void gemm_nt(const u16* __restrict__ A, const u16* __restrict__ B,
                                               float* __restrict__ C, int M, int N, int K) {
  __shared__ __align__(16) u16 sA[64 * 32];
  __shared__ __align__(16) u16 sB[128 * 32];
  const int tid = threadIdx.x;
  const int w = tid >> 6, lane = tid & 63, l15 = lane & 15;
  const int m0 = blockIdx.x * 64, n0 = blockIdx.y * 128;
  const int wm = (w >> 1) * 32, wn = (w & 1) * 64;

  f32x4 acc[2][4] = {};

  int sArow, sAcol;
  {
    int p = tid * 16;
    int row = p >> 6, oo = p & 63;
    int ol = oo ^ (((row >> 1) & 3) << 4);
    sArow = row; sAcol = ol >> 1;
  }
  int sBrow[2], sBcol[2];
#pragma unroll
  for (int i = 0; i < 2; ++i) {
    int p = i * 4096 + tid * 16;
    int row = p >> 6, oo = p & 63;
    int ol = oo ^ (((row >> 1) & 3) << 4);
    sBrow[i] = row; sBcol[i] = ol >> 1;
  }
  int aoff[2], boff[4];
  const int kb = (lane >> 4) * 16;
#pragma unroll
  for (int m = 0; m < 2; ++m) {
    int r = wm + m * 16 + l15;
    aoff[m] = r * 64 + (kb ^ (((r >> 1) & 3) << 4));
  }
#pragma unroll
  for (int n = 0; n < 4; ++n) {
    int r = wn + n * 16 + l15;
    boff[n] = r * 64 + (kb ^ (((r >> 1) & 3) << 4));
  }

  for (int k0 = 0; k0 < K; k0 += 32) {
    gll16(A + (size_t)(m0 + sArow) * K + k0 + sAcol, (u16*)((char*)sA + tid * 16));
#pragma unroll
    for (int i = 0; i < 2; ++i)
      gll16(B + (size_t)(n0 + sBrow[i]) * K + k0 + sBcol[i], (u16*)((char*)sB + i * 4096 + tid * 16));
    __syncthreads();
    bf16x8 af[2], bfr[4];
#pragma unroll
    for (int m = 0; m < 2; ++m) af[m] = *(const bf16x8*)((const char*)sA + aoff[m]);
#pragma unroll
    for (int n = 0; n < 4; ++n) bfr[n] = *(const bf16x8*)((const char*)sB + boff[n]);
#pragma unroll
    for (int m = 0; m < 2; ++m)
#pragma unroll
      for (int n = 0; n < 4; ++n)
        acc[m][n] = __builtin_amdgcn_mfma_f32_16x16x32_bf16(af[m], bfr[n], acc[m][n], 0, 0, 0);
    __syncthreads();
  }

#pragma unroll
  for (int m = 0; m < 2; ++m)
#pragma unroll
    for (int i = 0; i < 4; ++i) {
      int gr = m0 + wm + m * 16 + (lane >> 4) * 4 + i;
      float* crow = C + (size_t)gr * N + n0 + wn + l15;
#pragma unroll
      for (int n = 0; n < 4; ++n) crow[n * 16] = acc[m][n][i];
    }
}

// ---------------- QKV GEMM (64x128 tile), fused RMSNorm+RoPE; V written TRANSPOSED ----
// Wave tile 32 x 64: one wave spans exactly one head; he = (n0+wn)>>6 in 0..23.
// he<16 -> Q (norm+rope, *QSCALE); he<20 -> K (norm+rope); else V -> Vt[bh][d][s].
__global__ __launch_bounds__(256) void gemm_qkv(const u16* __restrict__ A, const u16* __restrict__ B,
                                                const float* __restrict__ qw, const float* __restrict__ kw,
                                                const float2* __restrict__ tab,
                                                u16* __restrict__ Qo, u16* __restrict__ Ko,
                                                u16* __restrict__ Vt, int K) {
  __shared__ __align__(16) u16 sA[64 * 32];
  __shared__ __align__(16) u16 sB[128 * 32];
  const int tid = threadIdx.x;
  const int w = tid >> 6, lane = tid & 63, l15 = lane & 15, lg = lane >> 4;
  const int m0 = blockIdx.x * 64, n0 = blockIdx.y * 128;
  const int wm = (w >> 1) * 32, wn = (w & 1) * 64;

  f32x4 acc[2][4] = {};

  int sArow, sAcol;
  {
    int p = tid * 16;
    int row = p >> 6, oo = p & 63;
    int ol = oo ^ (((row >> 1) & 3) << 4);
    sArow = row; sAcol = ol >> 1;
  }
  int sBrow[2], sBcol[2];
#pragma unroll
  for (int i = 0; i < 2; ++i) {
    int p = i * 4096 + tid * 16;
    int row = p >> 6, oo = p & 63;
    int ol = oo ^ (((row >> 1) & 3) << 4);
    sBrow[i] = row; sBcol[i] = ol >> 1;
  }
  int aoff[2], boff[4];
  const int kb = lg * 16;
#pragma unroll
  for (int m = 0; m < 2; ++m) {
    int r = wm + m * 16 + l15;
    aoff[m] = r * 64 + (kb ^ (((r >> 1) & 3) << 4));
  }
#pragma unroll
  for (int n = 0; n < 4; ++n) {
    int r = wn + n * 16 + l15;
    boff[n] = r * 64 + (kb ^ (((r >> 1) & 3) << 4));
  }

  for (int k0 = 0; k0 < K; k0 += 32) {
    gll16(A + (size_t)(m0 + sArow) * K + k0 + sAcol, (u16*)((char*)sA + tid * 16));
#pragma unroll
    for (int i = 0; i < 2; ++i)
      gll16(B + (size_t)(n0 + sBrow[i]) * K + k0 + sBcol[i], (u16*)((char*)sB + i * 4096 + tid * 16));
    __syncthreads();
    bf16x8 af[2], bfr[4];
#pragma unroll
    for (int m = 0; m < 2; ++m) af[m] = *(const bf16x8*)((const char*)sA + aoff[m]);
#pragma unroll
    for (int n = 0; n < 4; ++n) bfr[n] = *(const bf16x8*)((const char*)sB + boff[n]);
#pragma unroll
    for (int m = 0; m < 2; ++m)
#pragma unroll
      for (int n = 0; n < 4; ++n)
        acc[m][n] = __builtin_amdgcn_mfma_f32_16x16x32_bf16(af[m], bfr[n], acc[m][n], 0, 0, 0);
    __syncthreads();
  }

  const int he = (n0 + wn) >> 6;   // wave-uniform head index 0..23
  if (he < 20) {
    const float* wnorm = (he < 16) ? qw : kw;
    const float oscale = (he < 16) ? QSCALE : 1.0f;
    float wv[4];
#pragma unroll
    for (int n = 0; n < 4; ++n) wv[n] = wnorm[n * 16 + l15];
    float2 tj[4];
#pragma unroll
    for (int m = 0; m < 2; ++m)
#pragma unroll
      for (int i = 0; i < 4; ++i) {
        const int gr = m0 + wm + m * 16 + lg * 4 + i;
        const int s = gr & 2047, bb = gr >> 11;
        float ss = 0.f;
#pragma unroll
        for (int n = 0; n < 4; ++n) ss += acc[m][n][i] * acc[m][n][i];
        ss += __shfl_xor(ss, 8); ss += __shfl_xor(ss, 4);
        ss += __shfl_xor(ss, 2); ss += __shfl_xor(ss, 1);
        const float r = rsqrtf(ss * (1.0f / 64.0f) + 1.1920929e-7f);
#pragma unroll
        for (int n = 0; n < 4; ++n) tj[n] = tab[s * 32 + n * 8 + (l15 >> 1)];
        u16* orow = (he < 16)
          ? Qo + ((size_t)(bb * 16 + he) * 2048 + s) * 64 + l15
          : Ko + ((size_t)(bb * 4 + (he - 16)) * 2048 + s) * 64 + l15;
#pragma unroll
        for (int n = 0; n < 4; ++n) {
          float xn = acc[m][n][i] * r * wv[n];
          float p = __shfl_xor(xn, 1);
          float outv = ((l15 & 1) == 0) ? (xn * tj[n].x - p * tj[n].y)
                                        : (xn * tj[n].x + p * tj[n].y);
          orow[n * 16] = f2bf(outv * oscale);
        }
      }
  } else {
    // V: write transposed Vt[bh][d][s] directly (scatter u16 stores; 2/12 of blocks)
#pragma unroll
    for (int m = 0; m < 2; ++m)
#pragma unroll
      for (int i = 0; i < 4; ++i) {
        const int gr = m0 + wm + m * 16 + lg * 4 + i;
        const int s = gr & 2047, bb = gr >> 11;
        u16* vcol = Vt + ((size_t)(bb * 4 + (he - 20)) * 64 + l15) * 2048 + s;
#pragma unroll
        for (int n = 0; n < 4; ++n) vcol[(size_t)n * 16 * 2048] = f2bf(acc[m][n][i]);
      }
  }
}

// ---------------- Flash attention: r15 body (paired q-tiles + KV-parity, 24.5 KB LDS) ----
__global__ __launch_bounds__(256) void attn_fwd_pair(const u16* __restrict__ Q, const u16* __restrict__ Kg,
                                                     const u16* __restrict__ Vt,
                                                     u16* __restrict__ accP, float* __restrict__ lP) {
  __shared__ __align__(16) u16 sK[64 * 64];
  __shared__ __align__(16) u16 sV[64 * 64];
  __shared__ __align__(16) u16 sP[4][16 * 64];

  const int tid = threadIdx.x;
  const int w = tid >> 6, lane = tid & 63;
  const int l15 = lane & 15, lg = lane >> 4;
  const int qiA = blockIdx.x;
  const int qiB = 31 - qiA;
  const int z = blockIdx.z;
  const int bh = blockIdx.y, b = bh >> 4, h = bh & 15, kvh = h >> 2;

  const u16* Qp = Q + (size_t)(b * 16 + h) * 2048 * 64;
  const u16* Kp = Kg + (size_t)(b * 4 + kvh) * 2048 * 64;
  const u16* Vp = Vt + (size_t)(b * 4 + kvh) * 64 * 2048;

  const int q0s[2] = {qiA * 64, qiB * 64};
  bf16x8 qa[2][2];
#pragma unroll
  for (int s = 0; s < 2; ++s) {
    const u16* qrow = Qp + (size_t)(q0s[s] + w * 16 + l15) * 64 + lg * 8;
    qa[s][0] = *(const bf16x8*)qrow;
    qa[s][1] = *(const bf16x8*)(qrow + 32);
  }

  f32x4 acc[2][4] = {};
  float l_s[2] = {0.f, 0.f};

  const int srw = tid >> 2;
  const int scb = (tid & 3) * 32;
  const int swzS = (srw & 7) << 4;
  const int st0 = srw * 128 + (scb ^ swzS);
  const int st1 = srw * 128 + ((scb + 16) ^ swzS);
  const u16* kgp = Kp + (size_t)srw * 64 + (tid & 3) * 16;
  const u16* vgp = Vp + (size_t)srw * 2048 + (tid & 3) * 16;

  const int swzF = (l15 & 7) << 4;
  const int fo0 = (lg * 16) ^ swzF;
  const int fo1 = (64 + lg * 16) ^ swzF;

  u16x8 kr0 = *(const u16x8*)(kgp + (size_t)z * 64 * 64), kr1 = *(const u16x8*)(kgp + (size_t)z * 64 * 64 + 8);
  u16x8 vr0 = *(const u16x8*)(vgp + z * 64),              vr1 = *(const u16x8*)(vgp + z * 64 + 8);

  for (int t = z; t <= qiB; t += 2) {
    __syncthreads();
    *(u16x8*)((char*)sK + st0) = kr0; *(u16x8*)((char*)sK + st1) = kr1;
    *(u16x8*)((char*)sV + st0) = vr0; *(u16x8*)((char*)sV + st1) = vr1;
    __syncthreads();

    if (t + 2 <= qiB) {
      const u16* kg = kgp + (size_t)(t + 2) * 64 * 64;
      const u16* vg = vgp + (t + 2) * 64;
      kr0 = *(const u16x8*)kg; kr1 = *(const u16x8*)(kg + 8);
      vr0 = *(const u16x8*)vg; vr1 = *(const u16x8*)(vg + 8);
    }

    bf16x8 kf[4][2], vf[4][2];
#pragma unroll
    for (int ct = 0; ct < 4; ++ct) {
      const char* krow = (const char*)sK + (ct * 16 + l15) * 128;
      const char* vrow = (const char*)sV + (ct * 16 + l15) * 128;
      kf[ct][0] = *(const bf16x8*)(krow + fo0);
      kf[ct][1] = *(const bf16x8*)(krow + fo1);
      vf[ct][0] = *(const bf16x8*)(vrow + fo0);
      vf[ct][1] = *(const bf16x8*)(vrow + fo1);
    }

#pragma unroll
    for (int s = 0; s < 2; ++s) {
      if (s == 0 && t > qiA) continue;
      const int diag = s ? qiB : qiA;

      f32x4 st[4];
#pragma unroll
      for (int ct = 0; ct < 4; ++ct) {
        f32x4 s4 = {};
        s4 = __builtin_amdgcn_mfma_f32_16x16x32_bf16(kf[ct][0], qa[s][0], s4, 0, 0, 0);
        s4 = __builtin_amdgcn_mfma_f32_16x16x32_bf16(kf[ct][1], qa[s][1], s4, 0, 0, 0);
        st[ct] = s4;
      }

      if (t == diag) {
        const int ql = w * 16 + l15;
#pragma unroll
        for (int ct = 0; ct < 4; ++ct)
#pragma unroll
          for (int i = 0; i < 4; ++i)
            st[ct][i] = (ct * 16 + lg * 4 + i <= ql) ? st[ct][i] : -1e30f;
      }

      float ls = 0.f;
      const int swzP = (l15 & 7) << 4;
      char* prow = (char*)sP[w] + l15 * 128;
#pragma unroll
      for (int ct = 0; ct < 4; ++ct) {
        float p0 = exp2f(st[ct][0]), p1 = exp2f(st[ct][1]);
        float p2 = exp2f(st[ct][2]), p3 = exp2f(st[ct][3]);
        ls += (p0 + p1) + (p2 + p3);
        u32 lo = (u32)f2bfh(p0) | ((u32)f2bfh(p1) << 16);
        u32 hi = (u32)f2bfh(p2) | ((u32)f2bfh(p3) << 16);
        *(u32x2*)(prow + ((ct * 32 + lg * 8) ^ swzP)) = (u32x2){lo, hi};
      }
      l_s[s] += ls;

      bf16x8 pa0 = *(const bf16x8*)(prow + ((lg * 16) ^ swzP));
      bf16x8 pa1 = *(const bf16x8*)(prow + ((64 + lg * 16) ^ swzP));

#pragma unroll
      for (int n = 0; n < 4; ++n) {
        acc[s][n] = __builtin_amdgcn_mfma_f32_16x16x32_bf16(pa0, vf[n][0], acc[s][n], 0, 0, 0);
        acc[s][n] = __builtin_amdgcn_mfma_f32_16x16x32_bf16(pa1, vf[n][1], acc[s][n], 0, 0, 0);
      }
    }
  }

#pragma unroll
  for (int s = 0; s < 2; ++s) {
    float lv = l_s[s];
    lv += __shfl_xor(lv, 16);
    lv += __shfl_xor(lv, 32);
    if (lg == 0) {
      int qrow = q0s[s] + w * 16 + l15;
      lP[((size_t)z * 4096 + b * 2048 + qrow) * 16 + h] = lv;
    }
#pragma unroll
    for (int i = 0; i < 4; ++i) {
      int srowg = q0s[s] + w * 16 + lg * 4 + i;
      size_t rowbase = (size_t)z * 4096 + b * 2048 + srowg;
      u16* orow = accP + rowbase * 1024 + h * 64 + l15;
#pragma unroll
      for (int n = 0; n < 4; ++n) orow[n * 16] = f2bfh(acc[s][n][i]);
    }
  }
}

// ---------------- combine + gate: O = (a0+a1)/(l0+l1) * sigmoid(x[:12]@gw[h]) ----------
__global__ __launch_bounds__(256) void attn_combine(const u16* __restrict__ accP, const float* __restrict__ lP,
                                                    const float* __restrict__ x, const float* __restrict__ gw,
                                                    u16* __restrict__ attnh) {
  const size_t e = ((size_t)blockIdx.x * 256 + threadIdx.x) * 8;
  const int token = (int)(e >> 10);
  const int h = (int)((e >> 6) & 15);
  u16x8 a0 = *(const u16x8*)(accP + e);
  u16x8 a1 = *(const u16x8*)(accP + ((size_t)4096 << 10) + e);
  const size_t li = (size_t)token * 16 + h;
  float l = lP[li] + lP[(size_t)4096 * 16 + li];
  float gd = 0.f;
#pragma unroll
  for (int j = 0; j < 12; ++j) gd += x[(size_t)token * 1024 + j] * gw[h * 12 + j];
  float g = (1.0f / (1.0f + __expf(-gd))) / l;
  u16x8 o;
#pragma unroll
  for (int j = 0; j < 8; ++j) o[j] = f2bfh((bf2f(a0[j]) + bf2f(a1[j])) * g);
  *(u16x8*)(attnh + e) = o;
}

// ---------------- launch ----------------
extern "C" void kernel_launch(void* const* d_in, const int* in_sizes, int n_in,
                              void* d_out, int out_size, void* d_ws, size_t ws_size,
                              hipStream_t stream) {
  const float* x  = (const float*)d_in[0];
  const float* Wf = (const float*)d_in[1];
  const float* qw = (const float*)d_in[2];
  const float* kw = (const float*)d_in[3];
  const float* gw = (const float*)d_in[4];
  float* out = (float*)d_out;

  char* ws = (char*)d_ws;
  size_t off = 0;
  auto alloc = [&](size_t bytes) { void* p = ws + off; off += (bytes + 255) & ~(size_t)255; return p; };

  u16*    xb   = (u16*)alloc((size_t)4096 * 1024 * 2);
  u16*    wb   = (u16*)alloc((size_t)2560 * 1024 * 2);
  float2* tab  = (float2*)alloc((size_t)2048 * 32 * 8);
  u16*    Qb   = (u16*)alloc((size_t)2 * 16 * 2048 * 64 * 2);
  u16*    Kb   = (u16*)alloc((size_t)2 * 4 * 2048 * 64 * 2);
  u16*    Vtb  = (u16*)alloc((size_t)2 * 4 * 2048 * 64 * 2);
  float*  lP   = (float*)alloc((size_t)2 * 4096 * 16 * 4);
  u16*    accP = (u16*)alloc((size_t)2 * 4096 * 1024 * 2);
  // attnh aliases xb (dead after gemm_qkv)
  u16* attnh = xb;

  const int n4a = 4096 * 1024 / 4, n4b = 2560 * 1024 / 4;
  const int prep_total = n4a + n4b + 2048 * 32;
  prep_k<<<dim3((prep_total + 255) / 256), dim3(256), 0, stream>>>(x, xb, n4a, Wf, wb, n4b, tab);
  gemm_qkv<<<dim3(64, 12), dim3(256), 0, stream>>>(xb, wb, qw, kw, tab, Qb, Kb, Vtb, 1024);
  attn_fwd_pair<<<dim3(16, 32, 2), dim3(256), 0, stream>>>(Qb, Kb, Vtb, accP, lP);
  attn_combine<<<dim3(2048), dim3(256), 0, stream>>>(accP, lP, x, gw, attnh);
  gemm_nt<<<dim3(64, 8), dim3(256), 0, stream>>>(attnh, wb + (size_t)1536 * 1024, out, 4096, 1024, 1024);
}